// Round 4
// baseline (432.143 us; speedup 1.0000x reference)
//
#include <hip/hip_runtime.h>
#include <hip/hip_bf16.h>
#include <stdint.h>

// ---- problem constants (B=2, T=2048, C=1024, H=16, hs=64) ----
#define BSZ   2
#define TT    2048
#define NH    16
#define HS    64
#define CC    1024
#define C3    3072
#define MT    4096            // B*T rows
#define E10   4.5399929762484854e-05f   // exp(-10)

typedef __bf16 bf16;
typedef __bf16 bf16x8 __attribute__((ext_vector_type(8)));
typedef float  f32x4  __attribute__((ext_vector_type(4)));
typedef short  s16x4  __attribute__((ext_vector_type(4)));

#define AS1 __attribute__((address_space(1)))
#define AS3 __attribute__((address_space(3)))

__device__ __forceinline__ void glds16(const bf16* g, bf16* l) {
    __builtin_amdgcn_global_load_lds((const AS1 void*)g, (AS3 void*)l, 16, 0, 0);
}

// =====================================================================
// Input dtype detector: flag=0 -> bf16 inputs, flag=1 -> fp32 inputs.
// =====================================================================
__global__ void detect_dtype(const uint16_t* __restrict__ x, int* __restrict__ flag) {
    __shared__ int cnt;
    if (threadIdx.x == 0) cnt = 0;
    __syncthreads();
    int local = 0;
    for (int i = threadIdx.x; i < 512; i += 256) {
        uint16_t u = x[i];
        int e = (u >> 7) & 0xFF;
        if (e >= 96 && e <= 159) local++;
    }
    atomicAdd(&cnt, local);
    __syncthreads();
    if (threadIdx.x == 0) *flag = (cnt >= 461) ? 0 : 1;
}

// fp32 -> bf16 convert (no-op when flag==0)
__global__ void convert_k(const float* __restrict__ src, bf16* __restrict__ dst,
                          int n8, const int* __restrict__ flag) {
    if (*flag == 0) return;
    int i = blockIdx.x * blockDim.x + threadIdx.x;
    if (i >= n8) return;
    const float4* s = reinterpret_cast<const float4*>(src) + (long)i * 2;
    float4 a = s[0], b = s[1];
    bf16x8 r;
    r[0] = (bf16)a.x; r[1] = (bf16)a.y; r[2] = (bf16)a.z; r[3] = (bf16)a.w;
    r[4] = (bf16)b.x; r[5] = (bf16)b.y; r[6] = (bf16)b.z; r[7] = (bf16)b.w;
    reinterpret_cast<bf16x8*>(dst)[i] = r;
}

// =====================================================================
// GEMM: C[M,N] = A[M,K] * B[N,K]^T  — m97 structure (unchanged, passing)
// =====================================================================
__global__ __launch_bounds__(256)
void gemm_bt(const bf16* __restrict__ A0, const bf16* __restrict__ A1,
             const bf16* __restrict__ B0, const bf16* __restrict__ B1,
             void* __restrict__ C, const int* __restrict__ flag,
             int M, int N, int K, int lda, int ldb, int ldc, int cf32_dyn) {
    __shared__ bf16 As[128 * 32];
    __shared__ bf16 Bs[128 * 32];

    const int f = *flag;
    const bf16* A = f ? A1 : A0;
    const bf16* B = f ? B1 : B0;
    const int cf32 = cf32_dyn & f;

    const int tid  = threadIdx.x;
    const int lane = tid & 63;
    const int wave = tid >> 6;
    const int wm   = wave >> 1;
    const int wn   = wave & 1;
    const int quad = lane >> 4;
    const int l16  = lane & 15;

    const int row0 = blockIdx.y * 128;
    const int col0 = blockIdx.x * 128;

    const int srow = tid >> 2;
    const int skk  = (tid & 3) * 8;

    const bf16* Ap = A + (long)(row0 + srow) * lda + skk;
    const bf16* Bp = B + (long)(col0 + srow) * ldb + skk;
    bf16* AsW = As + wave * 512;
    bf16* BsW = Bs + wave * 512;

    f32x4 acc[4][4] = {};

    for (int k0 = 0; k0 < K; k0 += 32) {
        glds16(Ap + k0,                  AsW);
        glds16(Ap + (long)64 * lda + k0, AsW + 2048);
        glds16(Bp + k0,                  BsW);
        glds16(Bp + (long)64 * ldb + k0, BsW + 2048);
        __syncthreads();

        bf16x8 af[4], bfv[4];
#pragma unroll
        for (int mi = 0; mi < 4; ++mi)
            af[mi] = *reinterpret_cast<const bf16x8*>(&As[(wm * 64 + mi * 16 + l16) * 32 + quad * 8]);
#pragma unroll
        for (int ni = 0; ni < 4; ++ni)
            bfv[ni] = *reinterpret_cast<const bf16x8*>(&Bs[(wn * 64 + ni * 16 + l16) * 32 + quad * 8]);
#pragma unroll
        for (int mi = 0; mi < 4; ++mi)
#pragma unroll
            for (int ni = 0; ni < 4; ++ni)
                acc[mi][ni] = __builtin_amdgcn_mfma_f32_16x16x32_bf16(af[mi], bfv[ni], acc[mi][ni], 0, 0, 0);
        __syncthreads();
    }

#pragma unroll
    for (int mi = 0; mi < 4; ++mi)
#pragma unroll
        for (int ni = 0; ni < 4; ++ni)
#pragma unroll
            for (int r = 0; r < 4; ++r) {
                int row = row0 + wm * 64 + mi * 16 + quad * 4 + r;
                int col = col0 + wn * 64 + ni * 16 + l16;
                float v = acc[mi][ni][r];
                if (cf32) ((float*)C)[(long)row * ldc + col] = v;
                else      ((bf16*)C)[(long)row * ldc + col] = (bf16)v;
            }
}

// =====================================================================
// In-place K repack: within each head-row of 64 d's (8 chunks of 16B),
// chunk order d-chunk c=ks*4+quad -> dst chunk quad*2+ks. After repack,
// the A-fragment (m=key, k=quad*8+j, both ks halves) is 32B contiguous.
// Threads own disjoint rows -> in-place safe.
// =====================================================================
__global__ __launch_bounds__(256)
void krepack(bf16* __restrict__ qkv) {
    long id = (long)blockIdx.x * 256 + threadIdx.x;   // 0..65535
    int m = (int)(id >> 4), h = (int)(id & 15);
    bf16* p = qkv + (long)m * C3 + CC + h * 64;
    uint4 s[8];
#pragma unroll
    for (int c = 0; c < 8; ++c) s[c] = *reinterpret_cast<uint4*>(p + c * 8);
#pragma unroll
    for (int i = 0; i < 8; ++i)
        *reinterpret_cast<uint4*>(p + i * 8) = s[(i & 1) * 4 + (i >> 1)];
}

// =====================================================================
// V transpose: Vt[bh][d][tc*64 + sigma(t_local)] = V[t][d], where sigma
// swaps key bits[5:4]<->[3:2] so a lane's 4 K=16-fragments (g=0..3) for
// its quad are 32B contiguous. sigma is an involution.
// =====================================================================
__global__ __launch_bounds__(256)
void vtranspose(const bf16* __restrict__ qkv, bf16* __restrict__ Vt) {
    __shared__ bf16 Vl[64 * 72];
    const int tc = blockIdx.x, bh = blockIdx.y;
    const int b = bh >> 4, h = bh & 15;
    const int tid = threadIdx.x;
    const int row = tid >> 2, doff = (tid & 3) * 16;
    const bf16* src = qkv + ((long)b * TT + tc * 64 + row) * C3 + 2 * CC + h * 64 + doff;
    *reinterpret_cast<bf16x8*>(&Vl[row * 72 + doff])     = *reinterpret_cast<const bf16x8*>(src);
    *reinterpret_cast<bf16x8*>(&Vl[row * 72 + doff + 8]) = *reinterpret_cast<const bf16x8*>(src + 8);
    __syncthreads();
    const int d = tid >> 2, poff = (tid & 3) * 16;
    bf16 tmp[16];
#pragma unroll
    for (int i = 0; i < 16; ++i) {
        int pos = poff + i;
        int tl = ((pos & 12) << 2) | ((pos & 48) >> 2) | (pos & 3);   // sigma
        tmp[i] = Vl[tl * 72 + d];
    }
    bf16* dst = Vt + ((long)bh * 64 + d) * 2048 + tc * 64 + poff;
    *reinterpret_cast<bf16x8*>(dst)     = *reinterpret_cast<bf16x8*>(tmp);
    *reinterpret_cast<bf16x8*>(dst + 8) = *reinterpret_cast<bf16x8*>(tmp + 8);
}

// Suffix sums over 64-key tiles from Vt rows (permutation-invariant).
__global__ void vsuffix(const bf16* __restrict__ Vt, float* __restrict__ Vts) {
    const int bh = blockIdx.x, d = threadIdx.x;
    const bf16* row = Vt + ((long)bh * 64 + d) * 2048;
    Vts[((long)bh * 33 + 32) * 64 + d] = 0.f;
    float acc = 0.f;
    for (int kt = 31; kt >= 0; --kt) {
        float s = 0.f;
#pragma unroll
        for (int i = 0; i < 8; ++i) {
            bf16x8 v = *reinterpret_cast<const bf16x8*>(row + kt * 64 + i * 8);
#pragma unroll
            for (int j = 0; j < 8; ++j) s += (float)v[j];
        }
        acc += s;
        Vts[((long)bh * 33 + kt) * 64 + d] = acc;
    }
}

// =====================================================================
// LDS-free flash attention, soft (-10) mask, M=0 softmax.
// S^T = K·Q^T (16x16x32): C-layout col=l16=qrow, row=quad*4+r=key.
// That IS the B-operand layout of K=16 MFMA -> O^T = V^T·P^T via
// mfma_f32_16x16x16bf16_1k with P^T passed straight from registers.
// Wave owns 16 q-rows; no barriers, no LDS. Future keys: closed-form
// suffix-V correction (uniform weight exp(-10)).
// =====================================================================
__global__ __launch_bounds__(256)
void attn(bf16* __restrict__ qkv, const bf16* __restrict__ Vt,
          const float* __restrict__ Vts) {
    const int tid  = threadIdx.x;
    const int lane = tid & 63;
    const int wave = tid >> 6;
    const int quad = lane >> 4;
    const int l16  = lane & 15;

    const int chunk = 31 - blockIdx.x;   // heavy blocks first
    const int h = blockIdx.y, b = blockIdx.z;
    const int qbase = chunk * 64 + wave * 16;
    const long rbase = (long)b * TT;

    // Q fragments (B-operand: n=l16=qrow, k=quad*8+j), register-resident
    const bf16* qp = qkv + (rbase + qbase + l16) * C3 + h * HS;
    bf16x8 qf0 = *reinterpret_cast<const bf16x8*>(qp + quad * 8);
    bf16x8 qf1 = *reinterpret_cast<const bf16x8*>(qp + 32 + quad * 8);

    f32x4 O[4] = {};
    float lp = 0.f;
    const int ktend = chunk + 1;
    const bf16* kb = qkv + rbase * C3 + CC + h * HS + quad * 16;  // repacked rows
    const bf16* vb = Vt + ((long)(b * NH + h) * 64 + l16) * 2048 + quad * 16;

    for (int kt = 0; kt < ktend; ++kt) {
        const int k0 = kt * 64;

        // S^T = K·Q^T  (A = K-frag m=key l16, k-chunks 32B contiguous)
        f32x4 S[4] = {};
#pragma unroll
        for (int g = 0; g < 4; ++g) {
            const bf16* kr = kb + (long)(k0 + g * 16 + l16) * C3;
            bf16x8 kf0 = *reinterpret_cast<const bf16x8*>(kr);
            bf16x8 kf1 = *reinterpret_cast<const bf16x8*>(kr + 8);
            S[g] = __builtin_amdgcn_mfma_f32_16x16x32_bf16(kf0, qf0, S[g], 0, 0, 0);
            S[g] = __builtin_amdgcn_mfma_f32_16x16x32_bf16(kf1, qf1, S[g], 0, 0, 0);
        }

        // P^T = exp(S^T/8) with soft mask; accumulate per-lane denom; pack bf16
        const int q = qbase + l16;
        s16x4 pk[4];
#pragma unroll
        for (int g = 0; g < 4; ++g) {
#pragma unroll
            for (int r = 0; r < 4; ++r) {
                int key = k0 + g * 16 + quad * 4 + r;
                float p = (key > q) ? E10 : __expf(S[g][r] * 0.125f);
                lp += p;
                bf16 pb = (bf16)p;
                union { bf16 bh_; short s_; } u;
                u.bh_ = pb;
                pk[g][r] = u.s_;
            }
        }

        // O^T += V^T·P^T  (K=16 MFMA; V-frags 32B contiguous via sigma)
#pragma unroll
        for (int dg = 0; dg < 4; ++dg) {
            const bf16* vr = vb + (long)dg * 16 * 2048 + k0;
            s16x4 v0 = *reinterpret_cast<const s16x4*>(vr);
            s16x4 v1 = *reinterpret_cast<const s16x4*>(vr + 4);
            s16x4 v2 = *reinterpret_cast<const s16x4*>(vr + 8);
            s16x4 v3 = *reinterpret_cast<const s16x4*>(vr + 12);
            O[dg] = __builtin_amdgcn_mfma_f32_16x16x16bf16_1k(v0, pk[0], O[dg], 0, 0, 0);
            O[dg] = __builtin_amdgcn_mfma_f32_16x16x16bf16_1k(v1, pk[1], O[dg], 0, 0, 0);
            O[dg] = __builtin_amdgcn_mfma_f32_16x16x16bf16_1k(v2, pk[2], O[dg], 0, 0, 0);
            O[dg] = __builtin_amdgcn_mfma_f32_16x16x16bf16_1k(v3, pk[3], O[dg], 0, 0, 0);
        }
    }

    // denom: sum the 4 quads (same qrow l16 lives in all quads)
    lp += __shfl_xor(lp, 16, 64);
    lp += __shfl_xor(lp, 32, 64);

    const int nfut = TT - ktend * 64;
    const float l = lp + (float)nfut * E10;
    const float invl = 1.0f / l;
    const float* vfp = Vts + ((long)(b * NH + h) * 33 + ktend) * 64 + quad * 4;

    // y write: O^T C-layout -> 4 packed 8B stores per lane (d runs of 4)
    bf16* yp = qkv + (rbase + qbase + l16) * C3 + h * HS;
#pragma unroll
    for (int dg = 0; dg < 4; ++dg) {
        bf16 outv[4];
#pragma unroll
        for (int r = 0; r < 4; ++r) {
            float o = O[dg][r] + E10 * vfp[dg * 16 + r];
            outv[r] = (bf16)(o * invl);
        }
        *reinterpret_cast<uint2*>(yp + dg * 16 + quad * 4) =
            *reinterpret_cast<uint2*>(outv);
    }
}

// =====================================================================
extern "C" void kernel_launch(void* const* d_in, const int* in_sizes, int n_in,
                              void* d_out, int out_size, void* d_ws, size_t ws_size,
                              hipStream_t stream) {
    const void* x      = d_in[0];
    const void* w_attn = d_in[1];
    const void* w_proj = d_in[2];

    // ws (~27.6 MB): qkv | flag | Vts | wp_cvt
    char* ws = (char*)d_ws;
    bf16*  qkv    = (bf16*)ws;                                   // 25,165,824 B
    int*   flag   = (int*)(ws + (size_t)MT * C3 * 2);
    float* Vts    = (float*)(ws + (size_t)MT * C3 * 2 + 256);    //   270,336 B
    bf16*  wp_cvt = (bf16*)((char*)Vts + 32 * 33 * 64 * 4);      // 2,097,152 B

    // d_out scratch (provably dead-by-ordering):
    //   x_cvt [0..8.39MB] consumed by gemm1, then Vt [0..8.39MB] written by
    //   vtranspose, consumed by attn; gemm2 finally writes d_out for real.
    bf16* x_cvt  = (bf16*)d_out;
    bf16* wa_cvt = (bf16*)d_out + (size_t)MT * CC;
    bf16* Vtg    = (bf16*)d_out;                       // 32*64*2048*2 = 8,388,608 B

    detect_dtype<<<1, 256, 0, stream>>>((const uint16_t*)x, flag);
    convert_k<<<(MT * CC / 8 + 255) / 256, 256, 0, stream>>>((const float*)x, x_cvt, MT * CC / 8, flag);
    convert_k<<<(C3 * CC / 8 + 255) / 256, 256, 0, stream>>>((const float*)w_attn, wa_cvt, C3 * CC / 8, flag);
    convert_k<<<(CC * CC / 8 + 255) / 256, 256, 0, stream>>>((const float*)w_proj, wp_cvt, CC * CC / 8, flag);

    // gemm1: qkv = x @ w_attn^T  [4096, 3072]
    gemm_bt<<<dim3(C3 / 128, MT / 128), 256, 0, stream>>>(
        (const bf16*)x, x_cvt, (const bf16*)w_attn, wa_cvt, qkv, flag,
        MT, C3, CC, CC, CC, C3, /*cf32*/0);

    // V transpose (+sigma pack) into d_out scratch, then suffix sums
    vtranspose<<<dim3(32, BSZ * NH), 256, 0, stream>>>(qkv, Vtg);
    vsuffix<<<dim3(BSZ * NH), dim3(64), 0, stream>>>(Vtg, Vts);

    // in-place K chunk repack (after gemm1, before attn)
    krepack<<<256, 256, 0, stream>>>(qkv);

    // LDS-free attention; y overwrites Q columns of qkv
    attn<<<dim3(32, NH, BSZ), 256, 0, stream>>>(qkv, Vtg, Vts);

    // gemm2: out = y @ w_proj^T  [4096, 1024]
    gemm_bt<<<dim3(CC / 128, MT / 128), 256, 0, stream>>>(
        qkv, qkv, (const bf16*)w_proj, wp_cvt, d_out, flag,
        MT, CC, CC, C3, CC, CC, /*cf32*/1);
}

// Round 5
// 261.692 us; speedup vs baseline: 1.6513x; 1.6513x over previous
//
#include <hip/hip_runtime.h>
#include <hip/hip_bf16.h>
#include <stdint.h>

// ---- problem constants (B=2, T=2048, C=1024, H=16, hs=64) ----
#define BSZ   2
#define TT    2048
#define NH    16
#define HS    64
#define CC    1024
#define C3    3072
#define MT    4096            // B*T rows
#define E10   4.5399929762484854e-05f   // exp(-10)

typedef __bf16 bf16;
typedef __bf16 bf16x8 __attribute__((ext_vector_type(8)));
typedef float  f32x4  __attribute__((ext_vector_type(4)));
typedef short  s16x4  __attribute__((ext_vector_type(4)));

#define AS1 __attribute__((address_space(1)))
#define AS3 __attribute__((address_space(3)))

__device__ __forceinline__ void glds16(const bf16* g, bf16* l) {
    __builtin_amdgcn_global_load_lds((const AS1 void*)g, (AS3 void*)l, 16, 0, 0);
}

// =====================================================================
// Input dtype detector: flag=0 -> bf16 inputs, flag=1 -> fp32 inputs.
// =====================================================================
__global__ void detect_dtype(const uint16_t* __restrict__ x, int* __restrict__ flag) {
    __shared__ int cnt;
    if (threadIdx.x == 0) cnt = 0;
    __syncthreads();
    int local = 0;
    for (int i = threadIdx.x; i < 512; i += 256) {
        uint16_t u = x[i];
        int e = (u >> 7) & 0xFF;
        if (e >= 96 && e <= 159) local++;
    }
    atomicAdd(&cnt, local);
    __syncthreads();
    if (threadIdx.x == 0) *flag = (cnt >= 461) ? 0 : 1;
}

// fp32 -> bf16 convert (no-op when flag==0)
__global__ void convert_k(const float* __restrict__ src, bf16* __restrict__ dst,
                          int n8, const int* __restrict__ flag) {
    if (*flag == 0) return;
    int i = blockIdx.x * blockDim.x + threadIdx.x;
    if (i >= n8) return;
    const float4* s = reinterpret_cast<const float4*>(src) + (long)i * 2;
    float4 a = s[0], b = s[1];
    bf16x8 r;
    r[0] = (bf16)a.x; r[1] = (bf16)a.y; r[2] = (bf16)a.z; r[3] = (bf16)a.w;
    r[4] = (bf16)b.x; r[5] = (bf16)b.y; r[6] = (bf16)b.z; r[7] = (bf16)b.w;
    reinterpret_cast<bf16x8*>(dst)[i] = r;
}

// =====================================================================
// GEMM: C[M,N] = A[M,K] * B[N,K]^T  — m97 structure (unchanged, passing)
// =====================================================================
__global__ __launch_bounds__(256)
void gemm_bt(const bf16* __restrict__ A0, const bf16* __restrict__ A1,
             const bf16* __restrict__ B0, const bf16* __restrict__ B1,
             void* __restrict__ C, const int* __restrict__ flag,
             int M, int N, int K, int lda, int ldb, int ldc, int cf32_dyn) {
    __shared__ bf16 As[128 * 32];
    __shared__ bf16 Bs[128 * 32];

    const int f = *flag;
    const bf16* A = f ? A1 : A0;
    const bf16* B = f ? B1 : B0;
    const int cf32 = cf32_dyn & f;

    const int tid  = threadIdx.x;
    const int lane = tid & 63;
    const int wave = tid >> 6;
    const int wm   = wave >> 1;
    const int wn   = wave & 1;
    const int quad = lane >> 4;
    const int l16  = lane & 15;

    const int row0 = blockIdx.y * 128;
    const int col0 = blockIdx.x * 128;

    const int srow = tid >> 2;
    const int skk  = (tid & 3) * 8;

    const bf16* Ap = A + (long)(row0 + srow) * lda + skk;
    const bf16* Bp = B + (long)(col0 + srow) * ldb + skk;
    bf16* AsW = As + wave * 512;
    bf16* BsW = Bs + wave * 512;

    f32x4 acc[4][4] = {};

    for (int k0 = 0; k0 < K; k0 += 32) {
        glds16(Ap + k0,                  AsW);
        glds16(Ap + (long)64 * lda + k0, AsW + 2048);
        glds16(Bp + k0,                  BsW);
        glds16(Bp + (long)64 * ldb + k0, BsW + 2048);
        __syncthreads();

        bf16x8 af[4], bfv[4];
#pragma unroll
        for (int mi = 0; mi < 4; ++mi)
            af[mi] = *reinterpret_cast<const bf16x8*>(&As[(wm * 64 + mi * 16 + l16) * 32 + quad * 8]);
#pragma unroll
        for (int ni = 0; ni < 4; ++ni)
            bfv[ni] = *reinterpret_cast<const bf16x8*>(&Bs[(wn * 64 + ni * 16 + l16) * 32 + quad * 8]);
#pragma unroll
        for (int mi = 0; mi < 4; ++mi)
#pragma unroll
            for (int ni = 0; ni < 4; ++ni)
                acc[mi][ni] = __builtin_amdgcn_mfma_f32_16x16x32_bf16(af[mi], bfv[ni], acc[mi][ni], 0, 0, 0);
        __syncthreads();
    }

#pragma unroll
    for (int mi = 0; mi < 4; ++mi)
#pragma unroll
        for (int ni = 0; ni < 4; ++ni)
#pragma unroll
            for (int r = 0; r < 4; ++r) {
                int row = row0 + wm * 64 + mi * 16 + quad * 4 + r;
                int col = col0 + wn * 64 + ni * 16 + l16;
                float v = acc[mi][ni][r];
                if (cf32) ((float*)C)[(long)row * ldc + col] = v;
                else      ((bf16*)C)[(long)row * ldc + col] = (bf16)v;
            }
}

// =====================================================================
// V transpose: Vt[bh][d][tc*64 + sigma(t_local)] = V[t][d]; sigma swaps
// key bits[5:4]<->[3:2] so a lane's 4 K=16 A-fragments are 32B
// contiguous per quad (round-4-verified).
// =====================================================================
__global__ __launch_bounds__(256)
void vtranspose(const bf16* __restrict__ qkv, bf16* __restrict__ Vt) {
    __shared__ bf16 Vl[64 * 72];
    const int tc = blockIdx.x, bh = blockIdx.y;
    const int b = bh >> 4, h = bh & 15;
    const int tid = threadIdx.x;
    const int row = tid >> 2, doff = (tid & 3) * 16;
    const bf16* src = qkv + ((long)b * TT + tc * 64 + row) * C3 + 2 * CC + h * 64 + doff;
    *reinterpret_cast<bf16x8*>(&Vl[row * 72 + doff])     = *reinterpret_cast<const bf16x8*>(src);
    *reinterpret_cast<bf16x8*>(&Vl[row * 72 + doff + 8]) = *reinterpret_cast<const bf16x8*>(src + 8);
    __syncthreads();
    const int d = tid >> 2, poff = (tid & 3) * 16;
    bf16 tmp[16];
#pragma unroll
    for (int i = 0; i < 16; ++i) {
        int pos = poff + i;
        int tl = ((pos & 12) << 2) | ((pos & 48) >> 2) | (pos & 3);   // sigma
        tmp[i] = Vl[tl * 72 + d];
    }
    bf16* dst = Vt + ((long)bh * 64 + d) * 2048 + tc * 64 + poff;
    *reinterpret_cast<bf16x8*>(dst)     = *reinterpret_cast<bf16x8*>(tmp);
    *reinterpret_cast<bf16x8*>(dst + 8) = *reinterpret_cast<bf16x8*>(tmp + 8);
}

// Suffix sums over 64-key tiles from Vt rows (permutation-invariant).
__global__ void vsuffix(const bf16* __restrict__ Vt, float* __restrict__ Vts) {
    const int bh = blockIdx.x, d = threadIdx.x;
    const bf16* row = Vt + ((long)bh * 64 + d) * 2048;
    Vts[((long)bh * 33 + 32) * 64 + d] = 0.f;
    float acc = 0.f;
    for (int kt = 31; kt >= 0; --kt) {
        float s = 0.f;
#pragma unroll
        for (int i = 0; i < 8; ++i) {
            bf16x8 v = *reinterpret_cast<const bf16x8*>(row + kt * 64 + i * 8);
#pragma unroll
            for (int j = 0; j < 8; ++j) s += (float)v[j];
        }
        acc += s;
        Vts[((long)bh * 33 + kt) * 64 + d] = acc;
    }
}

// =====================================================================
// Flash attention: transposed compute (S^T = K·Q^T; O^T = V^T·P^T via
// K=16 MFMA, P^T register-direct) + glds16 LDS staging with XOR chunk
// swizzle (LDS chunk c' = c ^ (row&7); DMA can't pad, so the swizzle is
// folded into per-lane DMA *source* addresses; fragment reads then hit
// all 32 banks at 2 lanes/bank = free).
// Block = (b,h,128 q-rows); 4 waves x 32 rows (2 strips of 16).
// Soft mask: M=0 softmax + closed-form suffix-V future-key correction.
// =====================================================================
__global__ __launch_bounds__(256)
void attn(bf16* __restrict__ qkv, const bf16* __restrict__ Vt,
          const float* __restrict__ Vts) {
    __shared__ bf16 Ks[64 * 64];   // [key][chunk-swizzled d], 8KB
    __shared__ bf16 Vs[64 * 64];   // [d][chunk-swizzled key(sigma)], 8KB

    const int tid  = threadIdx.x;
    const int lane = tid & 63;
    const int wave = tid >> 6;
    const int quad = lane >> 4;
    const int l16  = lane & 15;

    const int chunk = 15 - blockIdx.x;   // heavy blocks first
    const int h = blockIdx.y, b = blockIdx.z;
    const int q0 = chunk * 128;
    const long rbase = (long)b * TT;

    // Q fragments per strip (B-operand: n=l16=qrow, k=quad*8+j)
    bf16x8 qf[2][2];
#pragma unroll
    for (int s = 0; s < 2; ++s) {
        const bf16* qp = qkv + (rbase + q0 + wave * 32 + s * 16 + l16) * C3 + h * HS;
        qf[s][0] = *reinterpret_cast<const bf16x8*>(qp + quad * 8);
        qf[s][1] = *reinterpret_cast<const bf16x8*>(qp + 32 + quad * 8);
    }

    f32x4 O[2][4] = {};
    float lp[2] = {0.f, 0.f};

    // DMA lane geometry: each wave stages rows [wave*16, wave*16+16) of
    // both K and Vt tiles in 2 issues; LDS chunk c' = lane&7 holds global
    // chunk c = (lane&7) ^ (row&7).
    const int rl  = lane >> 3;                    // 0..7
    const int cs  = (lane & 7) ^ rl;              // source chunk
    const int row0dma = wave * 16 + rl;
    const bf16* kgb = qkv + (rbase + row0dma) * C3 + CC + h * HS + cs * 8;
    const bf16* vgb = Vt + ((long)(b * NH + h) * 64 + row0dma) * 2048 + cs * 8;
    bf16* KsW = Ks + wave * 1024;                 // 128 chunks = 2KB per wave
    bf16* VsW = Vs + wave * 1024;

    const int sx = l16 & 7;                       // read-side swizzle key
    const int ktend = chunk * 2 + 2;

    for (int kt = 0; kt < ktend; ++kt) {
        __syncthreads();                          // prior tile reads done
        glds16(kgb + (long)(kt * 64) * C3,            KsW);
        glds16(kgb + (long)(kt * 64 + 8) * C3,        KsW + 512);
        glds16(vgb + kt * 64,                         VsW);
        glds16(vgb + (long)8 * 2048 + kt * 64,        VsW + 512);
        __syncthreads();                          // DMA drained

        // K fragments (A-operand: m=key=g*16+l16, k-halves read separately)
        bf16x8 kf0[4], kf1[4];
#pragma unroll
        for (int g = 0; g < 4; ++g) {
            const int krow = g * 16 + l16;
            kf0[g] = *reinterpret_cast<const bf16x8*>(&Ks[krow * 64 + ((quad ^ sx) * 8)]);
            kf1[g] = *reinterpret_cast<const bf16x8*>(&Ks[krow * 64 + (((4 + quad) ^ sx) * 8)]);
        }
        // V fragments (A-operand of K=16 PV; sigma-packed 32B per quad)
        s16x4 vf[4][4];
#pragma unroll
        for (int dg = 0; dg < 4; ++dg) {
            const int vrow = dg * 16 + l16;
            union { uint4 u; s16x4 s[2]; } ua, ub;
            ua.u = *reinterpret_cast<const uint4*>(&Vs[vrow * 64 + (((2 * quad) ^ sx) * 8)]);
            ub.u = *reinterpret_cast<const uint4*>(&Vs[vrow * 64 + (((2 * quad + 1) ^ sx) * 8)]);
            vf[dg][0] = ua.s[0]; vf[dg][1] = ua.s[1];
            vf[dg][2] = ub.s[0]; vf[dg][3] = ub.s[1];
        }

#pragma unroll
        for (int s = 0; s < 2; ++s) {
            // S^T = K·Q^T
            f32x4 S[4] = {};
#pragma unroll
            for (int g = 0; g < 4; ++g) {
                S[g] = __builtin_amdgcn_mfma_f32_16x16x32_bf16(kf0[g], qf[s][0], S[g], 0, 0, 0);
                S[g] = __builtin_amdgcn_mfma_f32_16x16x32_bf16(kf1[g], qf[s][1], S[g], 0, 0, 0);
            }
            // P^T = exp(S^T/8) + soft mask; per-lane denom; pack bf16
            const int q = q0 + wave * 32 + s * 16 + l16;
            s16x4 pk[4];
#pragma unroll
            for (int g = 0; g < 4; ++g) {
#pragma unroll
                for (int r = 0; r < 4; ++r) {
                    int key = kt * 64 + g * 16 + quad * 4 + r;
                    float p = (key > q) ? E10 : __expf(S[g][r] * 0.125f);
                    lp[s] += p;
                    union { bf16 b_; short s_; } u;
                    u.b_ = (bf16)p;
                    pk[g][r] = u.s_;
                }
            }
            // O^T += V^T·P^T
#pragma unroll
            for (int dg = 0; dg < 4; ++dg) {
                O[s][dg] = __builtin_amdgcn_mfma_f32_16x16x16bf16_1k(vf[dg][0], pk[0], O[s][dg], 0, 0, 0);
                O[s][dg] = __builtin_amdgcn_mfma_f32_16x16x16bf16_1k(vf[dg][1], pk[1], O[s][dg], 0, 0, 0);
                O[s][dg] = __builtin_amdgcn_mfma_f32_16x16x16bf16_1k(vf[dg][2], pk[2], O[s][dg], 0, 0, 0);
                O[s][dg] = __builtin_amdgcn_mfma_f32_16x16x16bf16_1k(vf[dg][3], pk[3], O[s][dg], 0, 0, 0);
            }
        }
    }

    // epilogue per strip: quad-reduce denom, future-key correction, y write
    const int nfut = TT - ktend * 64;
    const float* vfp = Vts + ((long)(b * NH + h) * 33 + ktend) * 64;
#pragma unroll
    for (int s = 0; s < 2; ++s) {
        float l = lp[s];
        l += __shfl_xor(l, 16, 64);
        l += __shfl_xor(l, 32, 64);
        l += (float)nfut * E10;
        const float invl = 1.0f / l;
        bf16* yp = qkv + (rbase + q0 + wave * 32 + s * 16 + l16) * C3 + h * HS;
#pragma unroll
        for (int dg = 0; dg < 4; ++dg) {
            bf16 outv[4];
#pragma unroll
            for (int r = 0; r < 4; ++r) {
                float o = O[s][dg][r] + E10 * vfp[dg * 16 + quad * 4 + r];
                outv[r] = (bf16)(o * invl);
            }
            *reinterpret_cast<uint2*>(yp + dg * 16 + quad * 4) =
                *reinterpret_cast<uint2*>(outv);
        }
    }
}

// =====================================================================
extern "C" void kernel_launch(void* const* d_in, const int* in_sizes, int n_in,
                              void* d_out, int out_size, void* d_ws, size_t ws_size,
                              hipStream_t stream) {
    const void* x      = d_in[0];
    const void* w_attn = d_in[1];
    const void* w_proj = d_in[2];

    // ws (~27.6 MB): qkv | flag | Vts | wp_cvt
    char* ws = (char*)d_ws;
    bf16*  qkv    = (bf16*)ws;                                   // 25,165,824 B
    int*   flag   = (int*)(ws + (size_t)MT * C3 * 2);
    float* Vts    = (float*)(ws + (size_t)MT * C3 * 2 + 256);    //   270,336 B
    bf16*  wp_cvt = (bf16*)((char*)Vts + 32 * 33 * 64 * 4);      // 2,097,152 B

    // d_out scratch (dead-by-ordering): x_cvt/wa_cvt consumed by gemm1,
    // then Vt written by vtranspose, consumed by attn; gemm2 writes d_out.
    bf16* x_cvt  = (bf16*)d_out;
    bf16* wa_cvt = (bf16*)d_out + (size_t)MT * CC;
    bf16* Vtg    = (bf16*)d_out;                       // 32*64*2048*2 = 8,388,608 B

    detect_dtype<<<1, 256, 0, stream>>>((const uint16_t*)x, flag);
    convert_k<<<(MT * CC / 8 + 255) / 256, 256, 0, stream>>>((const float*)x, x_cvt, MT * CC / 8, flag);
    convert_k<<<(C3 * CC / 8 + 255) / 256, 256, 0, stream>>>((const float*)w_attn, wa_cvt, C3 * CC / 8, flag);
    convert_k<<<(CC * CC / 8 + 255) / 256, 256, 0, stream>>>((const float*)w_proj, wp_cvt, CC * CC / 8, flag);

    // gemm1: qkv = x @ w_attn^T  [4096, 3072]
    gemm_bt<<<dim3(C3 / 128, MT / 128), 256, 0, stream>>>(
        (const bf16*)x, x_cvt, (const bf16*)w_attn, wa_cvt, qkv, flag,
        MT, C3, CC, CC, CC, C3, /*cf32*/0);

    // V transpose (+sigma pack) into d_out scratch, then suffix sums
    vtranspose<<<dim3(32, BSZ * NH), 256, 0, stream>>>(qkv, Vtg);
    vsuffix<<<dim3(BSZ * NH), dim3(64), 0, stream>>>(Vtg, Vts);

    // attention; y overwrites Q columns of qkv
    attn<<<dim3(16, NH, BSZ), 256, 0, stream>>>(qkv, Vtg, Vts);

    // gemm2: out = y @ w_proj^T  [4096, 1024]
    gemm_bt<<<dim3(CC / 128, MT / 128), 256, 0, stream>>>(
        qkv, qkv, (const bf16*)w_proj, wp_cvt, d_out, flag,
        MT, CC, CC, C3, CC, CC, /*cf32*/1);
}

// Round 6
// 214.676 us; speedup vs baseline: 2.0130x; 1.2190x over previous
//
#include <hip/hip_runtime.h>
#include <hip/hip_bf16.h>
#include <stdint.h>

// ---- problem constants (B=2, T=2048, C=1024, H=16, hs=64) ----
#define BSZ   2
#define TT    2048
#define NH    16
#define HS    64
#define CC    1024
#define C3    3072
#define MT    4096            // B*T rows
#define E10   4.5399929762484854e-05f   // exp(-10)

typedef __bf16 bf16;
typedef __bf16 bf16x8 __attribute__((ext_vector_type(8)));
typedef float  f32x4  __attribute__((ext_vector_type(4)));
typedef short  s16x4  __attribute__((ext_vector_type(4)));

#define AS1 __attribute__((address_space(1)))
#define AS3 __attribute__((address_space(3)))

__device__ __forceinline__ void glds16(const bf16* g, bf16* l) {
    __builtin_amdgcn_global_load_lds((const AS1 void*)g, (AS3 void*)l, 16, 0, 0);
}

// =====================================================================
// Input dtype detector: flag=0 -> bf16 inputs, flag=1 -> fp32 inputs.
// =====================================================================
__global__ void detect_dtype(const uint16_t* __restrict__ x, int* __restrict__ flag) {
    __shared__ int cnt;
    if (threadIdx.x == 0) cnt = 0;
    __syncthreads();
    int local = 0;
    for (int i = threadIdx.x; i < 512; i += 256) {
        uint16_t u = x[i];
        int e = (u >> 7) & 0xFF;
        if (e >= 96 && e <= 159) local++;
    }
    atomicAdd(&cnt, local);
    __syncthreads();
    if (threadIdx.x == 0) *flag = (cnt >= 461) ? 0 : 1;
}

// fp32 -> bf16 convert (no-op when flag==0)
__global__ void convert_k(const float* __restrict__ src, bf16* __restrict__ dst,
                          int n8, const int* __restrict__ flag) {
    if (*flag == 0) return;
    int i = blockIdx.x * blockDim.x + threadIdx.x;
    if (i >= n8) return;
    const float4* s = reinterpret_cast<const float4*>(src) + (long)i * 2;
    float4 a = s[0], b = s[1];
    bf16x8 r;
    r[0] = (bf16)a.x; r[1] = (bf16)a.y; r[2] = (bf16)a.z; r[3] = (bf16)a.w;
    r[4] = (bf16)b.x; r[5] = (bf16)b.y; r[6] = (bf16)b.z; r[7] = (bf16)b.w;
    reinterpret_cast<bf16x8*>(dst)[i] = r;
}

// =====================================================================
// GEMM: C[M,N] = A[M,K] * B[N,K]^T — dbuf single-barrier pipeline:
// prefetch tile k+1 via glds16 right after the barrier, compute tile k
// while the DMA flies; next barrier's vmcnt(0) drain lands after a full
// compute phase of overlap.
// =====================================================================
__global__ __launch_bounds__(256)
void gemm_bt(const bf16* __restrict__ A0, const bf16* __restrict__ A1,
             const bf16* __restrict__ B0, const bf16* __restrict__ B1,
             void* __restrict__ C, const int* __restrict__ flag,
             int M, int N, int K, int lda, int ldb, int ldc, int cf32_dyn) {
    __shared__ bf16 As[2][128 * 32];
    __shared__ bf16 Bs[2][128 * 32];

    const int f = *flag;
    const bf16* A = f ? A1 : A0;
    const bf16* B = f ? B1 : B0;
    const int cf32 = cf32_dyn & f;

    const int tid  = threadIdx.x;
    const int lane = tid & 63;
    const int wave = tid >> 6;
    const int wm   = wave >> 1;
    const int wn   = wave & 1;
    const int quad = lane >> 4;
    const int l16  = lane & 15;

    const int row0 = blockIdx.y * 128;
    const int col0 = blockIdx.x * 128;

    const int srow = tid >> 2;
    const int skk  = (tid & 3) * 8;

    const bf16* Ap = A + (long)(row0 + srow) * lda + skk;
    const bf16* Bp = B + (long)(col0 + srow) * ldb + skk;

    auto stage = [&](int k0, int buf) {
        glds16(Ap + k0,                  &As[buf][wave * 512]);
        glds16(Ap + (long)64 * lda + k0, &As[buf][wave * 512 + 2048]);
        glds16(Bp + k0,                  &Bs[buf][wave * 512]);
        glds16(Bp + (long)64 * ldb + k0, &Bs[buf][wave * 512 + 2048]);
    };

    f32x4 acc[4][4] = {};
    stage(0, 0);

    for (int k0 = 0; k0 < K; k0 += 32) {
        const int buf = (k0 >> 5) & 1;
        __syncthreads();                       // tile k ready; prev reads done
        if (k0 + 32 < K) stage(k0 + 32, buf ^ 1);   // overlaps compute below

        const bf16* Ac = As[buf];
        const bf16* Bc = Bs[buf];
        bf16x8 af[4], bfv[4];
#pragma unroll
        for (int mi = 0; mi < 4; ++mi)
            af[mi] = *reinterpret_cast<const bf16x8*>(&Ac[(wm * 64 + mi * 16 + l16) * 32 + quad * 8]);
#pragma unroll
        for (int ni = 0; ni < 4; ++ni)
            bfv[ni] = *reinterpret_cast<const bf16x8*>(&Bc[(wn * 64 + ni * 16 + l16) * 32 + quad * 8]);
#pragma unroll
        for (int mi = 0; mi < 4; ++mi)
#pragma unroll
            for (int ni = 0; ni < 4; ++ni)
                acc[mi][ni] = __builtin_amdgcn_mfma_f32_16x16x32_bf16(af[mi], bfv[ni], acc[mi][ni], 0, 0, 0);
    }

#pragma unroll
    for (int mi = 0; mi < 4; ++mi)
#pragma unroll
        for (int ni = 0; ni < 4; ++ni)
#pragma unroll
            for (int r = 0; r < 4; ++r) {
                int row = row0 + wm * 64 + mi * 16 + quad * 4 + r;
                int col = col0 + wn * 64 + ni * 16 + l16;
                float v = acc[mi][ni][r];
                if (cf32) ((float*)C)[(long)row * ldc + col] = v;
                else      ((bf16*)C)[(long)row * ldc + col] = (bf16)v;
            }
}

// =====================================================================
// V transpose: Vt[bh][d][tc*64 + sigma(t_local)] = V[t][d]; sigma swaps
// key bits[5:4]<->[3:2] (round-4/5-verified).
// =====================================================================
__global__ __launch_bounds__(256)
void vtranspose(const bf16* __restrict__ qkv, bf16* __restrict__ Vt) {
    __shared__ bf16 Vl[64 * 72];
    const int tc = blockIdx.x, bh = blockIdx.y;
    const int b = bh >> 4, h = bh & 15;
    const int tid = threadIdx.x;
    const int row = tid >> 2, doff = (tid & 3) * 16;
    const bf16* src = qkv + ((long)b * TT + tc * 64 + row) * C3 + 2 * CC + h * 64 + doff;
    *reinterpret_cast<bf16x8*>(&Vl[row * 72 + doff])     = *reinterpret_cast<const bf16x8*>(src);
    *reinterpret_cast<bf16x8*>(&Vl[row * 72 + doff + 8]) = *reinterpret_cast<const bf16x8*>(src + 8);
    __syncthreads();
    const int d = tid >> 2, poff = (tid & 3) * 16;
    bf16 tmp[16];
#pragma unroll
    for (int i = 0; i < 16; ++i) {
        int pos = poff + i;
        int tl = ((pos & 12) << 2) | ((pos & 48) >> 2) | (pos & 3);   // sigma
        tmp[i] = Vl[tl * 72 + d];
    }
    bf16* dst = Vt + ((long)bh * 64 + d) * 2048 + tc * 64 + poff;
    *reinterpret_cast<bf16x8*>(dst)     = *reinterpret_cast<bf16x8*>(tmp);
    *reinterpret_cast<bf16x8*>(dst + 8) = *reinterpret_cast<bf16x8*>(tmp + 8);
}

// =====================================================================
// Per-(bh,kt) V tile sums from Vt rows — parallel (1024 blocks) and
// coalesced (32B/thread), replacing round-5's 2048-thread serial scan.
// =====================================================================
__global__ __launch_bounds__(256)
void vtile2(const bf16* __restrict__ Vt, float* __restrict__ Vtile) {
    const int kt = blockIdx.x, bh = blockIdx.y;
    const int tid = threadIdx.x;
    const int d = tid >> 2, part = tid & 3;
    const bf16* p = Vt + ((long)bh * 64 + d) * 2048 + kt * 64 + part * 16;
    float s = 0.f;
#pragma unroll
    for (int i = 0; i < 2; ++i) {
        bf16x8 v = *reinterpret_cast<const bf16x8*>(p + i * 8);
#pragma unroll
        for (int j = 0; j < 8; ++j) s += (float)v[j];
    }
    s += __shfl_xor(s, 1, 64);
    s += __shfl_xor(s, 2, 64);
    if (part == 0) Vtile[((long)bh * 32 + kt) * 64 + d] = s;
}

// Suffix over 64-key tiles (tiny: 256KB in, 270KB out).
__global__ void vts_suffix(const float* __restrict__ Vtile, float* __restrict__ Vts) {
    const int bh = blockIdx.x, d = threadIdx.x;
    Vts[((long)bh * 33 + 32) * 64 + d] = 0.f;
    float acc = 0.f;
    for (int kt = 31; kt >= 0; --kt) {
        acc += Vtile[((long)bh * 32 + kt) * 64 + d];
        Vts[((long)bh * 33 + kt) * 64 + d] = acc;
    }
}

// =====================================================================
// Flash attention: transposed compute (S^T = K·Q^T; O^T = V^T·P^T via
// K=16 MFMA, P^T register-direct), glds16 staging with XOR chunk
// swizzle, 64-row chunks (grid 1024 = 4 blocks/CU), and single-barrier
// double-buffered DMA pipeline (prefetch tile kt+1 overlaps compute kt).
// Mask cmp only on the diagonal tile; sub-diagonal tiles are unmasked.
// Soft mask: M=0 softmax + closed-form suffix-V future-key correction.
// =====================================================================
__global__ __launch_bounds__(256)
void attn(bf16* __restrict__ qkv, const bf16* __restrict__ Vt,
          const float* __restrict__ Vts) {
    __shared__ bf16 Ks[2][64 * 64];   // [key][chunk-swizzled d], 8KB each
    __shared__ bf16 Vs[2][64 * 64];   // [d][sigma+chunk-swizzled key]

    const int tid  = threadIdx.x;
    const int lane = tid & 63;
    const int wave = tid >> 6;
    const int quad = lane >> 4;
    const int l16  = lane & 15;

    const int chunk = 31 - blockIdx.x;   // heavy blocks first
    const int h = blockIdx.y, b = blockIdx.z;
    const int q0 = chunk * 64;
    const long rbase = (long)b * TT;

    // Q fragment (B-operand: n=l16=qrow, k=quad*8+j), wave strip = 16 rows
    const bf16* qp = qkv + (rbase + q0 + wave * 16 + l16) * C3 + h * HS;
    bf16x8 qf0 = *reinterpret_cast<const bf16x8*>(qp + quad * 8);
    bf16x8 qf1 = *reinterpret_cast<const bf16x8*>(qp + 32 + quad * 8);

    f32x4 O[4] = {};
    float lp = 0.f;

    // DMA geometry: wave stages rows [wave*16, wave*16+16) of K and Vt
    // tiles; LDS chunk c' = lane&7 holds global chunk c = (lane&7)^(row&7).
    const int rl  = lane >> 3;
    const int cs  = (lane & 7) ^ rl;
    const int row0dma = wave * 16 + rl;
    const bf16* kgb = qkv + (rbase + row0dma) * C3 + CC + h * HS + cs * 8;
    const bf16* vgb = Vt + ((long)(b * NH + h) * 64 + row0dma) * 2048 + cs * 8;
    const int sx = l16 & 7;

    auto stage = [&](int kt, int buf) {
        glds16(kgb + (long)(kt * 64) * C3,     &Ks[buf][wave * 1024]);
        glds16(kgb + (long)(kt * 64 + 8) * C3, &Ks[buf][wave * 1024 + 512]);
        glds16(vgb + kt * 64,                  &Vs[buf][wave * 1024]);
        glds16(vgb + 8 * 2048 + kt * 64,       &Vs[buf][wave * 1024 + 512]);
    };

    const int ktend = chunk + 1;
    stage(0, 0);

    for (int kt = 0; kt < ktend; ++kt) {
        const int buf = kt & 1;
        __syncthreads();                     // tile kt ready; prior reads done
        if (kt + 1 < ktend) stage(kt + 1, buf ^ 1);   // overlaps compute

        const bf16* Kc = Ks[buf];
        const bf16* Vc = Vs[buf];

        // K fragments (A-operand: m=key=g*16+l16)
        bf16x8 kf0[4], kf1[4];
#pragma unroll
        for (int g = 0; g < 4; ++g) {
            const int krow = g * 16 + l16;
            kf0[g] = *reinterpret_cast<const bf16x8*>(&Kc[krow * 64 + ((quad ^ sx) * 8)]);
            kf1[g] = *reinterpret_cast<const bf16x8*>(&Kc[krow * 64 + (((4 + quad) ^ sx) * 8)]);
        }
        // V fragments (A-operand of K=16 PV; sigma-packed 32B per quad)
        s16x4 vf[4][4];
#pragma unroll
        for (int dg = 0; dg < 4; ++dg) {
            const int vrow = dg * 16 + l16;
            union { uint4 u; s16x4 s[2]; } ua, ub;
            ua.u = *reinterpret_cast<const uint4*>(&Vc[vrow * 64 + (((2 * quad) ^ sx) * 8)]);
            ub.u = *reinterpret_cast<const uint4*>(&Vc[vrow * 64 + (((2 * quad + 1) ^ sx) * 8)]);
            vf[dg][0] = ua.s[0]; vf[dg][1] = ua.s[1];
            vf[dg][2] = ub.s[0]; vf[dg][3] = ub.s[1];
        }

        // S^T = K·Q^T
        f32x4 S[4] = {};
#pragma unroll
        for (int g = 0; g < 4; ++g) {
            S[g] = __builtin_amdgcn_mfma_f32_16x16x32_bf16(kf0[g], qf0, S[g], 0, 0, 0);
            S[g] = __builtin_amdgcn_mfma_f32_16x16x32_bf16(kf1[g], qf1, S[g], 0, 0, 0);
        }

        // P^T = exp(S^T/8); mask only on the diagonal tile
        const bool dtile = (kt == chunk);
        const int ql = wave * 16 + l16;
        s16x4 pk[4];
#pragma unroll
        for (int g = 0; g < 4; ++g) {
#pragma unroll
            for (int r = 0; r < 4; ++r) {
                float p = __expf(S[g][r] * 0.125f);
                if (dtile) {
                    int kl = g * 16 + quad * 4 + r;
                    p = (kl > ql) ? E10 : p;
                }
                lp += p;
                union { bf16 b_; short s_; } u;
                u.b_ = (bf16)p;
                pk[g][r] = u.s_;
            }
        }

        // O^T += V^T·P^T
#pragma unroll
        for (int dg = 0; dg < 4; ++dg) {
            O[dg] = __builtin_amdgcn_mfma_f32_16x16x16bf16_1k(vf[dg][0], pk[0], O[dg], 0, 0, 0);
            O[dg] = __builtin_amdgcn_mfma_f32_16x16x16bf16_1k(vf[dg][1], pk[1], O[dg], 0, 0, 0);
            O[dg] = __builtin_amdgcn_mfma_f32_16x16x16bf16_1k(vf[dg][2], pk[2], O[dg], 0, 0, 0);
            O[dg] = __builtin_amdgcn_mfma_f32_16x16x16bf16_1k(vf[dg][3], pk[3], O[dg], 0, 0, 0);
        }
    }

    // denom across the 4 quads holding each qrow
    lp += __shfl_xor(lp, 16, 64);
    lp += __shfl_xor(lp, 32, 64);

    const int nfut = TT - ktend * 64;
    const float l = lp + (float)nfut * E10;
    const float invl = 1.0f / l;
    const float* vfp = Vts + ((long)(b * NH + h) * 33 + ktend) * 64;

    bf16* yp = qkv + (rbase + q0 + wave * 16 + l16) * C3 + h * HS;
#pragma unroll
    for (int dg = 0; dg < 4; ++dg) {
        bf16 outv[4];
#pragma unroll
        for (int r = 0; r < 4; ++r) {
            float o = O[dg][r] + E10 * vfp[dg * 16 + quad * 4 + r];
            outv[r] = (bf16)(o * invl);
        }
        *reinterpret_cast<uint2*>(yp + dg * 16 + quad * 4) =
            *reinterpret_cast<uint2*>(outv);
    }
}

// =====================================================================
extern "C" void kernel_launch(void* const* d_in, const int* in_sizes, int n_in,
                              void* d_out, int out_size, void* d_ws, size_t ws_size,
                              hipStream_t stream) {
    const void* x      = d_in[0];
    const void* w_attn = d_in[1];
    const void* w_proj = d_in[2];

    // ws (~27.8 MB): qkv | flag | Vts | wp_cvt | Vtile
    char* ws = (char*)d_ws;
    bf16*  qkv    = (bf16*)ws;                                   // 25,165,824 B
    int*   flag   = (int*)(ws + (size_t)MT * C3 * 2);
    float* Vts    = (float*)(ws + (size_t)MT * C3 * 2 + 256);    //   270,336 B
    bf16*  wp_cvt = (bf16*)((char*)Vts + 32 * 33 * 64 * 4);      // 2,097,152 B
    float* Vtile  = (float*)((char*)wp_cvt + (size_t)CC * CC * 2); // 262,144 B

    // d_out scratch (dead-by-ordering): x_cvt/wa_cvt consumed by gemm1,
    // then Vt written by vtranspose, consumed by attn; gemm2 writes d_out.
    bf16* x_cvt  = (bf16*)d_out;
    bf16* wa_cvt = (bf16*)d_out + (size_t)MT * CC;
    bf16* Vtg    = (bf16*)d_out;                       // 8,388,608 B

    detect_dtype<<<1, 256, 0, stream>>>((const uint16_t*)x, flag);
    convert_k<<<(MT * CC / 8 + 255) / 256, 256, 0, stream>>>((const float*)x, x_cvt, MT * CC / 8, flag);
    convert_k<<<(C3 * CC / 8 + 255) / 256, 256, 0, stream>>>((const float*)w_attn, wa_cvt, C3 * CC / 8, flag);
    convert_k<<<(CC * CC / 8 + 255) / 256, 256, 0, stream>>>((const float*)w_proj, wp_cvt, CC * CC / 8, flag);

    // gemm1: qkv = x @ w_attn^T  [4096, 3072]
    gemm_bt<<<dim3(C3 / 128, MT / 128), 256, 0, stream>>>(
        (const bf16*)x, x_cvt, (const bf16*)w_attn, wa_cvt, qkv, flag,
        MT, C3, CC, CC, CC, C3, /*cf32*/0);

    // V transpose (+sigma pack) into d_out scratch, tile sums, suffix
    vtranspose<<<dim3(32, BSZ * NH), 256, 0, stream>>>(qkv, Vtg);
    vtile2<<<dim3(32, BSZ * NH), 256, 0, stream>>>(Vtg, Vtile);
    vts_suffix<<<dim3(BSZ * NH), dim3(64), 0, stream>>>(Vtile, Vts);

    // attention; y overwrites Q columns of qkv
    attn<<<dim3(32, NH, BSZ), 256, 0, stream>>>(qkv, Vtg, Vts);

    // gemm2: out = y @ w_proj^T  [4096, 1024]
    gemm_bt<<<dim3(CC / 128, MT / 128), 256, 0, stream>>>(
        qkv, qkv, (const bf16*)w_proj, wp_cvt, d_out, flag,
        MT, CC, CC, C3, CC, CC, /*cf32*/1);
}

// Round 7
// 183.710 us; speedup vs baseline: 2.3523x; 1.1686x over previous
//
#include <hip/hip_runtime.h>
#include <hip/hip_bf16.h>
#include <stdint.h>

// ---- problem constants (B=2, T=2048, C=1024, H=16, hs=64) ----
#define BSZ   2
#define TT    2048
#define NH    16
#define HS    64
#define CC    1024
#define C3    3072
#define MT    4096            // B*T rows
#define E10   4.5399929762484854e-05f   // exp(-10)

typedef __bf16 bf16;
typedef __bf16 bf16x8 __attribute__((ext_vector_type(8)));
typedef float  f32x4  __attribute__((ext_vector_type(4)));
typedef short  s16x4  __attribute__((ext_vector_type(4)));

#define AS1 __attribute__((address_space(1)))
#define AS3 __attribute__((address_space(3)))

__device__ __forceinline__ void glds16(const bf16* g, bf16* l) {
    __builtin_amdgcn_global_load_lds((const AS1 void*)g, (AS3 void*)l, 16, 0, 0);
}

// =====================================================================
// Input dtype detector: flag=0 -> bf16 inputs, flag=1 -> fp32 inputs.
// =====================================================================
__global__ void detect_dtype(const uint16_t* __restrict__ x, int* __restrict__ flag) {
    __shared__ int cnt;
    if (threadIdx.x == 0) cnt = 0;
    __syncthreads();
    int local = 0;
    for (int i = threadIdx.x; i < 512; i += 256) {
        uint16_t u = x[i];
        int e = (u >> 7) & 0xFF;
        if (e >= 96 && e <= 159) local++;
    }
    atomicAdd(&cnt, local);
    __syncthreads();
    if (threadIdx.x == 0) *flag = (cnt >= 461) ? 0 : 1;
}

// fused fp32->bf16 converts for x / w_attn / w_proj (no-op when flag==0)
#define NX8  (MT * CC / 8)          // 524288
#define NWA8 (C3 * CC / 8)          // 393216
#define NWP8 (CC * CC / 8)          // 131072
__global__ __launch_bounds__(256)
void convert_all(const float* __restrict__ x, const float* __restrict__ wa,
                 const float* __restrict__ wp, bf16* __restrict__ xd,
                 bf16* __restrict__ wad, bf16* __restrict__ wpd,
                 const int* __restrict__ flag) {
    if (*flag == 0) return;
    long i = (long)blockIdx.x * 256 + threadIdx.x;
    const float* s; bf16* d; long off;
    if (i < NX8)             { s = x;  d = xd;  off = i; }
    else if (i < NX8 + NWA8) { s = wa; d = wad; off = i - NX8; }
    else                     { s = wp; d = wpd; off = i - NX8 - NWA8; }
    const float4* sp = reinterpret_cast<const float4*>(s) + off * 2;
    float4 a = sp[0], b = sp[1];
    bf16x8 r;
    r[0] = (bf16)a.x; r[1] = (bf16)a.y; r[2] = (bf16)a.z; r[3] = (bf16)a.w;
    r[4] = (bf16)b.x; r[5] = (bf16)b.y; r[6] = (bf16)b.z; r[7] = (bf16)b.w;
    reinterpret_cast<bf16x8*>(d)[off] = r;
}

// =====================================================================
// GEMM 128x128: C[M,N] = A[M,K]*B[N,K]^T, dbuf single-barrier pipeline.
// =====================================================================
__global__ __launch_bounds__(256)
void gemm_bt(const bf16* __restrict__ A0, const bf16* __restrict__ A1,
             const bf16* __restrict__ B0, const bf16* __restrict__ B1,
             void* __restrict__ C, const int* __restrict__ flag,
             int M, int N, int K, int lda, int ldb, int ldc, int cf32_dyn) {
    __shared__ bf16 As[2][128 * 32];
    __shared__ bf16 Bs[2][128 * 32];

    const int f = *flag;
    const bf16* A = f ? A1 : A0;
    const bf16* B = f ? B1 : B0;
    const int cf32 = cf32_dyn & f;

    const int tid  = threadIdx.x;
    const int lane = tid & 63;
    const int wave = tid >> 6;
    const int wm   = wave >> 1;
    const int wn   = wave & 1;
    const int quad = lane >> 4;
    const int l16  = lane & 15;

    const int row0 = blockIdx.y * 128;
    const int col0 = blockIdx.x * 128;

    const int srow = tid >> 2;
    const int skk  = (tid & 3) * 8;

    const bf16* Ap = A + (long)(row0 + srow) * lda + skk;
    const bf16* Bp = B + (long)(col0 + srow) * ldb + skk;

    auto stage = [&](int k0, int buf) {
        glds16(Ap + k0,                  &As[buf][wave * 512]);
        glds16(Ap + (long)64 * lda + k0, &As[buf][wave * 512 + 2048]);
        glds16(Bp + k0,                  &Bs[buf][wave * 512]);
        glds16(Bp + (long)64 * ldb + k0, &Bs[buf][wave * 512 + 2048]);
    };

    f32x4 acc[4][4] = {};
    stage(0, 0);

    for (int k0 = 0; k0 < K; k0 += 32) {
        const int buf = (k0 >> 5) & 1;
        __syncthreads();
        if (k0 + 32 < K) stage(k0 + 32, buf ^ 1);

        const bf16* Ac = As[buf];
        const bf16* Bc = Bs[buf];
        bf16x8 af[4], bfv[4];
#pragma unroll
        for (int mi = 0; mi < 4; ++mi)
            af[mi] = *reinterpret_cast<const bf16x8*>(&Ac[(wm * 64 + mi * 16 + l16) * 32 + quad * 8]);
#pragma unroll
        for (int ni = 0; ni < 4; ++ni)
            bfv[ni] = *reinterpret_cast<const bf16x8*>(&Bc[(wn * 64 + ni * 16 + l16) * 32 + quad * 8]);
#pragma unroll
        for (int mi = 0; mi < 4; ++mi)
#pragma unroll
            for (int ni = 0; ni < 4; ++ni)
                acc[mi][ni] = __builtin_amdgcn_mfma_f32_16x16x32_bf16(af[mi], bfv[ni], acc[mi][ni], 0, 0, 0);
    }

#pragma unroll
    for (int mi = 0; mi < 4; ++mi)
#pragma unroll
        for (int ni = 0; ni < 4; ++ni)
#pragma unroll
            for (int r = 0; r < 4; ++r) {
                int row = row0 + wm * 64 + mi * 16 + quad * 4 + r;
                int col = col0 + wn * 64 + ni * 16 + l16;
                float v = acc[mi][ni][r];
                if (cf32) ((float*)C)[(long)row * ldc + col] = v;
                else      ((bf16*)C)[(long)row * ldc + col] = (bf16)v;
            }
}

// =====================================================================
// GEMM 128x64 (for gemm2's small N): grid (N/64, M/128) = 512 blocks
// (2/CU vs 1/CU for the 128x128 tile). Waves 2x2 over 64-row x 32-col
// subtiles: acc[4][2].
// =====================================================================
__global__ __launch_bounds__(256)
void gemm_bt64(const bf16* __restrict__ A0, const bf16* __restrict__ A1,
               const bf16* __restrict__ B0, const bf16* __restrict__ B1,
               void* __restrict__ C, const int* __restrict__ flag,
               int M, int N, int K, int lda, int ldb, int ldc, int cf32_dyn) {
    __shared__ bf16 As[2][128 * 32];
    __shared__ bf16 Bs[2][64 * 32];

    const int f = *flag;
    const bf16* A = f ? A1 : A0;
    const bf16* B = f ? B1 : B0;
    const int cf32 = cf32_dyn & f;

    const int tid  = threadIdx.x;
    const int lane = tid & 63;
    const int wave = tid >> 6;
    const int wm   = wave >> 1;      // 64-row half
    const int wn   = wave & 1;       // 32-col half
    const int quad = lane >> 4;
    const int l16  = lane & 15;

    const int row0 = blockIdx.y * 128;
    const int col0 = blockIdx.x * 64;

    const int srow = tid >> 2;        // 0..63
    const int skk  = (tid & 3) * 8;

    const bf16* Ap = A + (long)(row0 + srow) * lda + skk;
    const bf16* Bp = B + (long)(col0 + srow) * ldb + skk;

    auto stage = [&](int k0, int buf) {
        glds16(Ap + k0,                  &As[buf][wave * 512]);
        glds16(Ap + (long)64 * lda + k0, &As[buf][wave * 512 + 2048]);
        glds16(Bp + k0,                  &Bs[buf][wave * 512]);
    };

    f32x4 acc[4][2] = {};
    stage(0, 0);

    for (int k0 = 0; k0 < K; k0 += 32) {
        const int buf = (k0 >> 5) & 1;
        __syncthreads();
        if (k0 + 32 < K) stage(k0 + 32, buf ^ 1);

        const bf16* Ac = As[buf];
        const bf16* Bc = Bs[buf];
        bf16x8 af[4], bfv[2];
#pragma unroll
        for (int mi = 0; mi < 4; ++mi)
            af[mi] = *reinterpret_cast<const bf16x8*>(&Ac[(wm * 64 + mi * 16 + l16) * 32 + quad * 8]);
#pragma unroll
        for (int ni = 0; ni < 2; ++ni)
            bfv[ni] = *reinterpret_cast<const bf16x8*>(&Bc[(wn * 32 + ni * 16 + l16) * 32 + quad * 8]);
#pragma unroll
        for (int mi = 0; mi < 4; ++mi)
#pragma unroll
            for (int ni = 0; ni < 2; ++ni)
                acc[mi][ni] = __builtin_amdgcn_mfma_f32_16x16x32_bf16(af[mi], bfv[ni], acc[mi][ni], 0, 0, 0);
    }

#pragma unroll
    for (int mi = 0; mi < 4; ++mi)
#pragma unroll
        for (int ni = 0; ni < 2; ++ni)
#pragma unroll
            for (int r = 0; r < 4; ++r) {
                int row = row0 + wm * 64 + mi * 16 + quad * 4 + r;
                int col = col0 + wn * 32 + ni * 16 + l16;
                float v = acc[mi][ni][r];
                if (cf32) ((float*)C)[(long)row * ldc + col] = v;
                else      ((bf16*)C)[(long)row * ldc + col] = (bf16)v;
            }
}

// =====================================================================
// V transpose (+sigma pack) fused with per-tile column sums: the tmp[16]
// registers hold exactly the tile-sum summands (sigma permutes within the
// tile -> sum invariant), so Vtile falls out for free.
// =====================================================================
__global__ __launch_bounds__(256)
void vtranspose(const bf16* __restrict__ qkv, bf16* __restrict__ Vt,
                float* __restrict__ Vtile) {
    __shared__ bf16 Vl[64 * 72];
    const int tc = blockIdx.x, bh = blockIdx.y;
    const int b = bh >> 4, h = bh & 15;
    const int tid = threadIdx.x;
    const int row = tid >> 2, doff = (tid & 3) * 16;
    const bf16* src = qkv + ((long)b * TT + tc * 64 + row) * C3 + 2 * CC + h * 64 + doff;
    *reinterpret_cast<bf16x8*>(&Vl[row * 72 + doff])     = *reinterpret_cast<const bf16x8*>(src);
    *reinterpret_cast<bf16x8*>(&Vl[row * 72 + doff + 8]) = *reinterpret_cast<const bf16x8*>(src + 8);
    __syncthreads();
    const int d = tid >> 2, poff = (tid & 3) * 16;
    bf16 tmp[16];
    float s = 0.f;
#pragma unroll
    for (int i = 0; i < 16; ++i) {
        int pos = poff + i;
        int tl = ((pos & 12) << 2) | ((pos & 48) >> 2) | (pos & 3);   // sigma
        tmp[i] = Vl[tl * 72 + d];
        s += (float)tmp[i];
    }
    bf16* dst = Vt + ((long)bh * 64 + d) * 2048 + tc * 64 + poff;
    *reinterpret_cast<bf16x8*>(dst)     = *reinterpret_cast<bf16x8*>(tmp);
    *reinterpret_cast<bf16x8*>(dst + 8) = *reinterpret_cast<bf16x8*>(tmp + 8);
    // tile-sum reduction across the 4 'part' lanes of each d
    s += __shfl_xor(s, 1, 64);
    s += __shfl_xor(s, 2, 64);
    if ((tid & 3) == 0)
        Vtile[((long)bh * 32 + tc) * 64 + d] = s;
}

// Suffix over 64-key tiles (tiny: 256KB in, 270KB out).
__global__ void vts_suffix(const float* __restrict__ Vtile, float* __restrict__ Vts) {
    const int bh = blockIdx.x, d = threadIdx.x;
    Vts[((long)bh * 33 + 32) * 64 + d] = 0.f;
    float acc = 0.f;
    for (int kt = 31; kt >= 0; --kt) {
        acc += Vtile[((long)bh * 32 + kt) * 64 + d];
        Vts[((long)bh * 33 + kt) * 64 + d] = acc;
    }
}

// =====================================================================
// Flash attention (transposed compute + glds16 swizzled staging + dbuf
// single-barrier pipeline), now with XCD-locality block swizzle:
// xcd = f&7, bh = (slot&3)*8 + xcd, chunk = 31 - (slot>>2).
// Each XCD serves 4 (b,h) pairs -> K+V working set 2MB, L2-resident.
// =====================================================================
__global__ __launch_bounds__(256)
void attn(bf16* __restrict__ qkv, const bf16* __restrict__ Vt,
          const float* __restrict__ Vts) {
    __shared__ bf16 Ks[2][64 * 64];
    __shared__ bf16 Vs[2][64 * 64];

    const int tid  = threadIdx.x;
    const int lane = tid & 63;
    const int wave = tid >> 6;
    const int quad = lane >> 4;
    const int l16  = lane & 15;

    // XCD-locality mapping (heavy chunks still dispatched first)
    const int f2   = blockIdx.x;
    const int xcd  = f2 & 7;
    const int slot = f2 >> 3;
    const int bh   = (slot & 3) * 8 + xcd;
    const int chunk = 31 - (slot >> 2);
    const int b = bh >> 4, h = bh & 15;
    const int q0 = chunk * 64;
    const long rbase = (long)b * TT;

    // Q fragment (B-operand: n=l16=qrow, k=quad*8+j), wave strip = 16 rows
    const bf16* qp = qkv + (rbase + q0 + wave * 16 + l16) * C3 + h * HS;
    bf16x8 qf0 = *reinterpret_cast<const bf16x8*>(qp + quad * 8);
    bf16x8 qf1 = *reinterpret_cast<const bf16x8*>(qp + 32 + quad * 8);

    f32x4 O[4] = {};
    float lp = 0.f;

    const int rl  = lane >> 3;
    const int cs  = (lane & 7) ^ rl;
    const int row0dma = wave * 16 + rl;
    const bf16* kgb = qkv + (rbase + row0dma) * C3 + CC + h * HS + cs * 8;
    const bf16* vgb = Vt + ((long)(b * NH + h) * 64 + row0dma) * 2048 + cs * 8;
    const int sx = l16 & 7;

    auto stage = [&](int kt, int buf) {
        glds16(kgb + (long)(kt * 64) * C3,     &Ks[buf][wave * 1024]);
        glds16(kgb + (long)(kt * 64 + 8) * C3, &Ks[buf][wave * 1024 + 512]);
        glds16(vgb + kt * 64,                  &Vs[buf][wave * 1024]);
        glds16(vgb + 8 * 2048 + kt * 64,       &Vs[buf][wave * 1024 + 512]);
    };

    const int ktend = chunk + 1;
    stage(0, 0);

    for (int kt = 0; kt < ktend; ++kt) {
        const int buf = kt & 1;
        __syncthreads();
        if (kt + 1 < ktend) stage(kt + 1, buf ^ 1);

        const bf16* Kc = Ks[buf];
        const bf16* Vc = Vs[buf];

        bf16x8 kf0[4], kf1[4];
#pragma unroll
        for (int g = 0; g < 4; ++g) {
            const int krow = g * 16 + l16;
            kf0[g] = *reinterpret_cast<const bf16x8*>(&Kc[krow * 64 + ((quad ^ sx) * 8)]);
            kf1[g] = *reinterpret_cast<const bf16x8*>(&Kc[krow * 64 + (((4 + quad) ^ sx) * 8)]);
        }
        s16x4 vf[4][4];
#pragma unroll
        for (int dg = 0; dg < 4; ++dg) {
            const int vrow = dg * 16 + l16;
            union { uint4 u; s16x4 s[2]; } ua, ub;
            ua.u = *reinterpret_cast<const uint4*>(&Vc[vrow * 64 + (((2 * quad) ^ sx) * 8)]);
            ub.u = *reinterpret_cast<const uint4*>(&Vc[vrow * 64 + (((2 * quad + 1) ^ sx) * 8)]);
            vf[dg][0] = ua.s[0]; vf[dg][1] = ua.s[1];
            vf[dg][2] = ub.s[0]; vf[dg][3] = ub.s[1];
        }

        f32x4 S[4] = {};
#pragma unroll
        for (int g = 0; g < 4; ++g) {
            S[g] = __builtin_amdgcn_mfma_f32_16x16x32_bf16(kf0[g], qf0, S[g], 0, 0, 0);
            S[g] = __builtin_amdgcn_mfma_f32_16x16x32_bf16(kf1[g], qf1, S[g], 0, 0, 0);
        }

        const bool dtile = (kt == chunk);
        const int ql = wave * 16 + l16;
        s16x4 pk[4];
#pragma unroll
        for (int g = 0; g < 4; ++g) {
#pragma unroll
            for (int r = 0; r < 4; ++r) {
                float p = __expf(S[g][r] * 0.125f);
                if (dtile) {
                    int kl = g * 16 + quad * 4 + r;
                    p = (kl > ql) ? E10 : p;
                }
                lp += p;
                union { bf16 b_; short s_; } u;
                u.b_ = (bf16)p;
                pk[g][r] = u.s_;
            }
        }

#pragma unroll
        for (int dg = 0; dg < 4; ++dg) {
            O[dg] = __builtin_amdgcn_mfma_f32_16x16x16bf16_1k(vf[dg][0], pk[0], O[dg], 0, 0, 0);
            O[dg] = __builtin_amdgcn_mfma_f32_16x16x16bf16_1k(vf[dg][1], pk[1], O[dg], 0, 0, 0);
            O[dg] = __builtin_amdgcn_mfma_f32_16x16x16bf16_1k(vf[dg][2], pk[2], O[dg], 0, 0, 0);
            O[dg] = __builtin_amdgcn_mfma_f32_16x16x16bf16_1k(vf[dg][3], pk[3], O[dg], 0, 0, 0);
        }
    }

    lp += __shfl_xor(lp, 16, 64);
    lp += __shfl_xor(lp, 32, 64);

    const int nfut = TT - ktend * 64;
    const float l = lp + (float)nfut * E10;
    const float invl = 1.0f / l;
    const float* vfp = Vts + ((long)(b * NH + h) * 33 + ktend) * 64;

    bf16* yp = qkv + (rbase + q0 + wave * 16 + l16) * C3 + h * HS;
#pragma unroll
    for (int dg = 0; dg < 4; ++dg) {
        bf16 outv[4];
#pragma unroll
        for (int r = 0; r < 4; ++r) {
            float o = O[dg][r] + E10 * vfp[dg * 16 + quad * 4 + r];
            outv[r] = (bf16)(o * invl);
        }
        *reinterpret_cast<uint2*>(yp + dg * 16 + quad * 4) =
            *reinterpret_cast<uint2*>(outv);
    }
}

// =====================================================================
extern "C" void kernel_launch(void* const* d_in, const int* in_sizes, int n_in,
                              void* d_out, int out_size, void* d_ws, size_t ws_size,
                              hipStream_t stream) {
    const void* x      = d_in[0];
    const void* w_attn = d_in[1];
    const void* w_proj = d_in[2];

    // ws (~27.8 MB): qkv | flag | Vts | wp_cvt | Vtile
    char* ws = (char*)d_ws;
    bf16*  qkv    = (bf16*)ws;                                   // 25,165,824 B
    int*   flag   = (int*)(ws + (size_t)MT * C3 * 2);
    float* Vts    = (float*)(ws + (size_t)MT * C3 * 2 + 256);    //   270,336 B
    bf16*  wp_cvt = (bf16*)((char*)Vts + 32 * 33 * 64 * 4);      // 2,097,152 B
    float* Vtile  = (float*)((char*)wp_cvt + (size_t)CC * CC * 2); // 262,144 B

    // d_out scratch (dead-by-ordering): x_cvt/wa_cvt consumed by gemm1,
    // then Vt written by vtranspose, consumed by attn; gemm2 writes d_out.
    bf16* x_cvt  = (bf16*)d_out;
    bf16* wa_cvt = (bf16*)d_out + (size_t)MT * CC;
    bf16* Vtg    = (bf16*)d_out;                       // 8,388,608 B

    detect_dtype<<<1, 256, 0, stream>>>((const uint16_t*)x, flag);
    convert_all<<<(NX8 + NWA8 + NWP8) / 256, 256, 0, stream>>>(
        (const float*)x, (const float*)w_attn, (const float*)w_proj,
        x_cvt, wa_cvt, wp_cvt, flag);

    // gemm1: qkv = x @ w_attn^T  [4096, 3072]
    gemm_bt<<<dim3(C3 / 128, MT / 128), 256, 0, stream>>>(
        (const bf16*)x, x_cvt, (const bf16*)w_attn, wa_cvt, qkv, flag,
        MT, C3, CC, CC, CC, C3, /*cf32*/0);

    // V transpose (+sigma pack, + fused tile sums), suffix
    vtranspose<<<dim3(32, BSZ * NH), 256, 0, stream>>>(qkv, Vtg, Vtile);
    vts_suffix<<<dim3(BSZ * NH), dim3(64), 0, stream>>>(Vtile, Vts);

    // attention (XCD-swizzled flat grid); y overwrites Q columns of qkv
    attn<<<dim3(1024), 256, 0, stream>>>(qkv, Vtg, Vts);

    // gemm2: out = y @ w_proj^T  [4096, 1024] — 128x64 tiles, 2 blocks/CU
    gemm_bt64<<<dim3(CC / 64, MT / 128), 256, 0, stream>>>(
        qkv, qkv, (const bf16*)w_proj, wp_cvt, d_out, flag,
        MT, CC, CC, C3, CC, CC, /*cf32*/1);
}

// Round 8
// 181.522 us; speedup vs baseline: 2.3807x; 1.0121x over previous
//
#include <hip/hip_runtime.h>
#include <hip/hip_bf16.h>
#include <stdint.h>

// ---- problem constants (B=2, T=2048, C=1024, H=16, hs=64) ----
#define BSZ   2
#define TT    2048
#define NH    16
#define HS    64
#define CC    1024
#define C3    3072
#define MT    4096            // B*T rows
#define E10   4.5399929762484854e-05f   // exp(-10)
#define SCL2  0.1803368801111204f       // 0.125 * log2(e)

typedef __bf16 bf16;
typedef __bf16 bf16x8 __attribute__((ext_vector_type(8)));
typedef float  f32x4  __attribute__((ext_vector_type(4)));
typedef short  s16x4  __attribute__((ext_vector_type(4)));

#define AS1 __attribute__((address_space(1)))
#define AS3 __attribute__((address_space(3)))

__device__ __forceinline__ void glds16(const bf16* g, bf16* l) {
    __builtin_amdgcn_global_load_lds((const AS1 void*)g, (AS3 void*)l, 16, 0, 0);
}

// =====================================================================
// Input dtype detector: flag=0 -> bf16 inputs, flag=1 -> fp32 inputs.
// =====================================================================
__global__ void detect_dtype(const uint16_t* __restrict__ x, int* __restrict__ flag) {
    __shared__ int cnt;
    if (threadIdx.x == 0) cnt = 0;
    __syncthreads();
    int local = 0;
    for (int i = threadIdx.x; i < 512; i += 256) {
        uint16_t u = x[i];
        int e = (u >> 7) & 0xFF;
        if (e >= 96 && e <= 159) local++;
    }
    atomicAdd(&cnt, local);
    __syncthreads();
    if (threadIdx.x == 0) *flag = (cnt >= 461) ? 0 : 1;
}

// fused fp32->bf16 converts for x / w_attn / w_proj (no-op when flag==0)
#define NX8  (MT * CC / 8)          // 524288
#define NWA8 (C3 * CC / 8)          // 393216
#define NWP8 (CC * CC / 8)          // 131072
__global__ __launch_bounds__(256)
void convert_all(const float* __restrict__ x, const float* __restrict__ wa,
                 const float* __restrict__ wp, bf16* __restrict__ xd,
                 bf16* __restrict__ wad, bf16* __restrict__ wpd,
                 const int* __restrict__ flag) {
    if (*flag == 0) return;
    long i = (long)blockIdx.x * 256 + threadIdx.x;
    const float* s; bf16* d; long off;
    if (i < NX8)             { s = x;  d = xd;  off = i; }
    else if (i < NX8 + NWA8) { s = wa; d = wad; off = i - NX8; }
    else                     { s = wp; d = wpd; off = i - NX8 - NWA8; }
    const float4* sp = reinterpret_cast<const float4*>(s) + off * 2;
    float4 a = sp[0], b = sp[1];
    bf16x8 r;
    r[0] = (bf16)a.x; r[1] = (bf16)a.y; r[2] = (bf16)a.z; r[3] = (bf16)a.w;
    r[4] = (bf16)b.x; r[5] = (bf16)b.y; r[6] = (bf16)b.z; r[7] = (bf16)b.w;
    reinterpret_cast<bf16x8*>(d)[off] = r;
}

// =====================================================================
// GEMM 128x128: C = A*B^T, dbuf single-barrier pipeline. Split store:
// col-blocks >= split_col write V directly in Vt layout (sigma-packed):
// tloc = mi*16+quad*4+r -> sigma(tloc) = quad*16+mi*4+r (r contiguous,
// 8B packed store). Kills the separate vtranspose pass.
// =====================================================================
__global__ __launch_bounds__(256)
void gemm_bt(const bf16* __restrict__ A0, const bf16* __restrict__ A1,
             const bf16* __restrict__ B0, const bf16* __restrict__ B1,
             void* __restrict__ Cmain, bf16* __restrict__ Cv,
             const int* __restrict__ flag,
             int M, int N, int K, int lda, int ldb, int ldc,
             int split_col, int cf32_dyn) {
    __shared__ bf16 As[2][128 * 32];
    __shared__ bf16 Bs[2][128 * 32];

    const int f = *flag;
    const bf16* A = f ? A1 : A0;
    const bf16* B = f ? B1 : B0;
    const int cf32 = cf32_dyn & f;

    const int tid  = threadIdx.x;
    const int lane = tid & 63;
    const int wave = tid >> 6;
    const int wm   = wave >> 1;
    const int wn   = wave & 1;
    const int quad = lane >> 4;
    const int l16  = lane & 15;

    const int row0 = blockIdx.y * 128;
    const int col0 = blockIdx.x * 128;

    const int srow = tid >> 2;
    const int skk  = (tid & 3) * 8;

    const bf16* Ap = A + (long)(row0 + srow) * lda + skk;
    const bf16* Bp = B + (long)(col0 + srow) * ldb + skk;

    auto stage = [&](int k0, int buf) {
        glds16(Ap + k0,                  &As[buf][wave * 512]);
        glds16(Ap + (long)64 * lda + k0, &As[buf][wave * 512 + 2048]);
        glds16(Bp + k0,                  &Bs[buf][wave * 512]);
        glds16(Bp + (long)64 * ldb + k0, &Bs[buf][wave * 512 + 2048]);
    };

    f32x4 acc[4][4] = {};
    stage(0, 0);

    for (int k0 = 0; k0 < K; k0 += 32) {
        const int buf = (k0 >> 5) & 1;
        __syncthreads();
        if (k0 + 32 < K) stage(k0 + 32, buf ^ 1);

        const bf16* Ac = As[buf];
        const bf16* Bc = Bs[buf];
        bf16x8 af[4], bfv[4];
#pragma unroll
        for (int mi = 0; mi < 4; ++mi)
            af[mi] = *reinterpret_cast<const bf16x8*>(&Ac[(wm * 64 + mi * 16 + l16) * 32 + quad * 8]);
#pragma unroll
        for (int ni = 0; ni < 4; ++ni)
            bfv[ni] = *reinterpret_cast<const bf16x8*>(&Bc[(wn * 64 + ni * 16 + l16) * 32 + quad * 8]);
#pragma unroll
        for (int mi = 0; mi < 4; ++mi)
#pragma unroll
            for (int ni = 0; ni < 4; ++ni)
                acc[mi][ni] = __builtin_amdgcn_mfma_f32_16x16x32_bf16(af[mi], bfv[ni], acc[mi][ni], 0, 0, 0);
    }

    if (split_col < 0 || col0 < split_col) {
        // main store (C/D layout: col=l16, row=quad*4+reg)
#pragma unroll
        for (int mi = 0; mi < 4; ++mi)
#pragma unroll
            for (int ni = 0; ni < 4; ++ni)
#pragma unroll
                for (int r = 0; r < 4; ++r) {
                    int row = row0 + wm * 64 + mi * 16 + quad * 4 + r;
                    int col = col0 + wn * 64 + ni * 16 + l16;
                    float v = acc[mi][ni][r];
                    if (cf32) ((float*)Cmain)[(long)row * ldc + col] = v;
                    else      ((bf16*)Cmain)[(long)row * ldc + col] = (bf16)v;
                }
    } else {
        // V store in Vt[bh][d][tc*64 + sigma(tloc)] layout
        const int h  = (col0 - split_col + wn * 64) >> 6;   // wave-uniform
        const int bq = row0 >> 11;
        const int tc = ((row0 & 2047) >> 6) + wm;
#pragma unroll
        for (int ni = 0; ni < 4; ++ni) {
            long vrow = (long)(bq * NH + h) * 64 + ni * 16 + l16;
#pragma unroll
            for (int mi = 0; mi < 4; ++mi) {
                bf16 outv[4];
#pragma unroll
                for (int r = 0; r < 4; ++r) outv[r] = (bf16)acc[mi][ni][r];
                *reinterpret_cast<uint2*>(&Cv[vrow * 2048 + tc * 64 + quad * 16 + mi * 4]) =
                    *reinterpret_cast<uint2*>(outv);
            }
        }
    }
}

// =====================================================================
// GEMM 128x64 (gemm2): grid 512 = 2 blocks/CU. acc[4][2].
// =====================================================================
__global__ __launch_bounds__(256)
void gemm_bt64(const bf16* __restrict__ A0, const bf16* __restrict__ A1,
               const bf16* __restrict__ B0, const bf16* __restrict__ B1,
               void* __restrict__ C, const int* __restrict__ flag,
               int M, int N, int K, int lda, int ldb, int ldc, int cf32_dyn) {
    __shared__ bf16 As[2][128 * 32];
    __shared__ bf16 Bs[2][64 * 32];

    const int f = *flag;
    const bf16* A = f ? A1 : A0;
    const bf16* B = f ? B1 : B0;
    const int cf32 = cf32_dyn & f;

    const int tid  = threadIdx.x;
    const int lane = tid & 63;
    const int wave = tid >> 6;
    const int wm   = wave >> 1;
    const int wn   = wave & 1;
    const int quad = lane >> 4;
    const int l16  = lane & 15;

    const int row0 = blockIdx.y * 128;
    const int col0 = blockIdx.x * 64;

    const int srow = tid >> 2;
    const int skk  = (tid & 3) * 8;

    const bf16* Ap = A + (long)(row0 + srow) * lda + skk;
    const bf16* Bp = B + (long)(col0 + srow) * ldb + skk;

    auto stage = [&](int k0, int buf) {
        glds16(Ap + k0,                  &As[buf][wave * 512]);
        glds16(Ap + (long)64 * lda + k0, &As[buf][wave * 512 + 2048]);
        glds16(Bp + k0,                  &Bs[buf][wave * 512]);
    };

    f32x4 acc[4][2] = {};
    stage(0, 0);

    for (int k0 = 0; k0 < K; k0 += 32) {
        const int buf = (k0 >> 5) & 1;
        __syncthreads();
        if (k0 + 32 < K) stage(k0 + 32, buf ^ 1);

        const bf16* Ac = As[buf];
        const bf16* Bc = Bs[buf];
        bf16x8 af[4], bfv[2];
#pragma unroll
        for (int mi = 0; mi < 4; ++mi)
            af[mi] = *reinterpret_cast<const bf16x8*>(&Ac[(wm * 64 + mi * 16 + l16) * 32 + quad * 8]);
#pragma unroll
        for (int ni = 0; ni < 2; ++ni)
            bfv[ni] = *reinterpret_cast<const bf16x8*>(&Bc[(wn * 32 + ni * 16 + l16) * 32 + quad * 8]);
#pragma unroll
        for (int mi = 0; mi < 4; ++mi)
#pragma unroll
            for (int ni = 0; ni < 2; ++ni)
                acc[mi][ni] = __builtin_amdgcn_mfma_f32_16x16x32_bf16(af[mi], bfv[ni], acc[mi][ni], 0, 0, 0);
    }

#pragma unroll
    for (int mi = 0; mi < 4; ++mi)
#pragma unroll
        for (int ni = 0; ni < 2; ++ni)
#pragma unroll
            for (int r = 0; r < 4; ++r) {
                int row = row0 + wm * 64 + mi * 16 + quad * 4 + r;
                int col = col0 + wn * 32 + ni * 16 + l16;
                float v = acc[mi][ni][r];
                if (cf32) ((float*)C)[(long)row * ldc + col] = v;
                else      ((bf16*)C)[(long)row * ldc + col] = (bf16)v;
            }
}

// =====================================================================
// Per-(bh,kt) V tile sums from Vt rows (sigma permutes within a tile ->
// sum invariant). 1024 blocks, coalesced 32B/thread.
// =====================================================================
__global__ __launch_bounds__(256)
void vtile2(const bf16* __restrict__ Vt, float* __restrict__ Vtile) {
    const int kt = blockIdx.x, bh = blockIdx.y;
    const int tid = threadIdx.x;
    const int d = tid >> 2, part = tid & 3;
    const bf16* p = Vt + ((long)bh * 64 + d) * 2048 + kt * 64 + part * 16;
    float s = 0.f;
#pragma unroll
    for (int i = 0; i < 2; ++i) {
        bf16x8 v = *reinterpret_cast<const bf16x8*>(p + i * 8);
#pragma unroll
        for (int j = 0; j < 8; ++j) s += (float)v[j];
    }
    s += __shfl_xor(s, 1, 64);
    s += __shfl_xor(s, 2, 64);
    if (part == 0) Vtile[((long)bh * 32 + kt) * 64 + d] = s;
}

// Suffix over 64-key tiles (tiny).
__global__ void vts_suffix(const float* __restrict__ Vtile, float* __restrict__ Vts) {
    const int bh = blockIdx.x, d = threadIdx.x;
    Vts[((long)bh * 33 + 32) * 64 + d] = 0.f;
    float acc = 0.f;
    for (int kt = 31; kt >= 0; --kt) {
        acc += Vtile[((long)bh * 32 + kt) * 64 + d];
        Vts[((long)bh * 33 + kt) * 64 + d] = acc;
    }
}

// =====================================================================
// Flash attention: transposed compute + glds16 swizzled staging + dbuf
// single-barrier pipeline + XCD-locality swizzle. qk row stride 2048
// (Q cols 0..1023, K cols 1024..2047).
// =====================================================================
__global__ __launch_bounds__(256)
void attn(bf16* __restrict__ qk, const bf16* __restrict__ Vt,
          const float* __restrict__ Vts) {
    __shared__ bf16 Ks[2][64 * 64];
    __shared__ bf16 Vs[2][64 * 64];

    const int tid  = threadIdx.x;
    const int lane = tid & 63;
    const int wave = tid >> 6;
    const int quad = lane >> 4;
    const int l16  = lane & 15;

    const int f2   = blockIdx.x;
    const int xcd  = f2 & 7;
    const int slot = f2 >> 3;
    const int bh   = (slot & 3) * 8 + xcd;
    const int chunk = 31 - (slot >> 2);
    const int b = bh >> 4, h = bh & 15;
    const int q0 = chunk * 64;
    const long rbase = (long)b * TT;

    const bf16* qp = qk + (rbase + q0 + wave * 16 + l16) * 2048 + h * HS;
    bf16x8 qf0 = *reinterpret_cast<const bf16x8*>(qp + quad * 8);
    bf16x8 qf1 = *reinterpret_cast<const bf16x8*>(qp + 32 + quad * 8);

    f32x4 O[4] = {};
    float lp = 0.f;

    const int rl  = lane >> 3;
    const int cs  = (lane & 7) ^ rl;
    const int row0dma = wave * 16 + rl;
    const bf16* kgb = qk + (rbase + row0dma) * 2048 + CC + h * HS + cs * 8;
    const bf16* vgb = Vt + ((long)(b * NH + h) * 64 + row0dma) * 2048 + cs * 8;
    const int sx = l16 & 7;

    auto stage = [&](int kt, int buf) {
        glds16(kgb + (long)(kt * 64) * 2048,     &Ks[buf][wave * 1024]);
        glds16(kgb + (long)(kt * 64 + 8) * 2048, &Ks[buf][wave * 1024 + 512]);
        glds16(vgb + kt * 64,                    &Vs[buf][wave * 1024]);
        glds16(vgb + 8 * 2048 + kt * 64,         &Vs[buf][wave * 1024 + 512]);
    };

    const int ktend = chunk + 1;
    stage(0, 0);

    for (int kt = 0; kt < ktend; ++kt) {
        const int buf = kt & 1;
        __syncthreads();
        if (kt + 1 < ktend) stage(kt + 1, buf ^ 1);

        const bf16* Kc = Ks[buf];
        const bf16* Vc = Vs[buf];

        bf16x8 kf0[4], kf1[4];
#pragma unroll
        for (int g = 0; g < 4; ++g) {
            const int krow = g * 16 + l16;
            kf0[g] = *reinterpret_cast<const bf16x8*>(&Kc[krow * 64 + ((quad ^ sx) * 8)]);
            kf1[g] = *reinterpret_cast<const bf16x8*>(&Kc[krow * 64 + (((4 + quad) ^ sx) * 8)]);
        }
        s16x4 vf[4][4];
#pragma unroll
        for (int dg = 0; dg < 4; ++dg) {
            const int vrow = dg * 16 + l16;
            union { uint4 u; s16x4 s[2]; } ua, ub;
            ua.u = *reinterpret_cast<const uint4*>(&Vc[vrow * 64 + (((2 * quad) ^ sx) * 8)]);
            ub.u = *reinterpret_cast<const uint4*>(&Vc[vrow * 64 + (((2 * quad + 1) ^ sx) * 8)]);
            vf[dg][0] = ua.s[0]; vf[dg][1] = ua.s[1];
            vf[dg][2] = ub.s[0]; vf[dg][3] = ub.s[1];
        }

        f32x4 S[4] = {};
#pragma unroll
        for (int g = 0; g < 4; ++g) {
            S[g] = __builtin_amdgcn_mfma_f32_16x16x32_bf16(kf0[g], qf0, S[g], 0, 0, 0);
            S[g] = __builtin_amdgcn_mfma_f32_16x16x32_bf16(kf1[g], qf1, S[g], 0, 0, 0);
        }

        const bool dtile = (kt == chunk);
        const int ql = wave * 16 + l16;
        s16x4 pk[4];
#pragma unroll
        for (int g = 0; g < 4; ++g) {
#pragma unroll
            for (int r = 0; r < 4; ++r) {
                float p = __builtin_exp2f(S[g][r] * SCL2);
                if (dtile) {
                    int kl = g * 16 + quad * 4 + r;
                    p = (kl > ql) ? E10 : p;
                }
                lp += p;
                union { bf16 b_; short s_; } u;
                u.b_ = (bf16)p;
                pk[g][r] = u.s_;
            }
        }

#pragma unroll
        for (int dg = 0; dg < 4; ++dg) {
            O[dg] = __builtin_amdgcn_mfma_f32_16x16x16bf16_1k(vf[dg][0], pk[0], O[dg], 0, 0, 0);
            O[dg] = __builtin_amdgcn_mfma_f32_16x16x16bf16_1k(vf[dg][1], pk[1], O[dg], 0, 0, 0);
            O[dg] = __builtin_amdgcn_mfma_f32_16x16x16bf16_1k(vf[dg][2], pk[2], O[dg], 0, 0, 0);
            O[dg] = __builtin_amdgcn_mfma_f32_16x16x16bf16_1k(vf[dg][3], pk[3], O[dg], 0, 0, 0);
        }
    }

    lp += __shfl_xor(lp, 16, 64);
    lp += __shfl_xor(lp, 32, 64);

    const int nfut = TT - ktend * 64;
    const float l = lp + (float)nfut * E10;
    const float invl = 1.0f / l;
    const float* vfp = Vts + ((long)(b * NH + h) * 33 + ktend) * 64;

    bf16* yp = qk + (rbase + q0 + wave * 16 + l16) * 2048 + h * HS;
#pragma unroll
    for (int dg = 0; dg < 4; ++dg) {
        bf16 outv[4];
#pragma unroll
        for (int r = 0; r < 4; ++r) {
            float o = O[dg][r] + E10 * vfp[dg * 16 + quad * 4 + r];
            outv[r] = (bf16)(o * invl);
        }
        *reinterpret_cast<uint2*>(yp + dg * 16 + quad * 4) =
            *reinterpret_cast<uint2*>(outv);
    }
}

// =====================================================================
extern "C" void kernel_launch(void* const* d_in, const int* in_sizes, int n_in,
                              void* d_out, int out_size, void* d_ws, size_t ws_size,
                              hipStream_t stream) {
    const void* x      = d_in[0];
    const void* w_attn = d_in[1];
    const void* w_proj = d_in[2];

    // ws (~27.8 MB): qk | Vt | flag | Vts | wp_cvt | Vtile
    char* ws = (char*)d_ws;
    bf16*  qk     = (bf16*)ws;                                    // 16,777,216 B
    bf16*  Vt     = (bf16*)(ws + (size_t)MT * 2048 * 2);          //  8,388,608 B
    char*  p2     = ws + (size_t)MT * 2048 * 2 + (size_t)32 * 64 * 2048 * 2;
    int*   flag   = (int*)p2;
    float* Vts    = (float*)(p2 + 256);                           //    270,336 B
    bf16*  wp_cvt = (bf16*)(p2 + 256 + 32 * 33 * 64 * 4);         //  2,097,152 B
    float* Vtile  = (float*)((char*)wp_cvt + (size_t)CC * CC * 2);//    262,144 B

    // d_out scratch (dead-by-ordering): x_cvt/wa_cvt consumed by gemm1;
    // gemm2 is the only writer of d_out afterwards.
    bf16* x_cvt  = (bf16*)d_out;
    bf16* wa_cvt = (bf16*)d_out + (size_t)MT * CC;

    detect_dtype<<<1, 256, 0, stream>>>((const uint16_t*)x, flag);
    convert_all<<<(NX8 + NWA8 + NWP8) / 256, 256, 0, stream>>>(
        (const float*)x, (const float*)w_attn, (const float*)w_proj,
        x_cvt, wa_cvt, wp_cvt, flag);

    // gemm1: qkv projection. cols<2048 (Q,K) -> qk (ldc 2048);
    // cols>=2048 (V) -> Vt directly (sigma-packed layout).
    gemm_bt<<<dim3(C3 / 128, MT / 128), 256, 0, stream>>>(
        (const bf16*)x, x_cvt, (const bf16*)w_attn, wa_cvt, qk, Vt, flag,
        MT, C3, CC, CC, CC, /*ldc*/2048, /*split*/2048, /*cf32*/0);

    // V tile sums + suffix (soft-mask correction inputs)
    vtile2<<<dim3(32, BSZ * NH), 256, 0, stream>>>(Vt, Vtile);
    vts_suffix<<<dim3(BSZ * NH), dim3(64), 0, stream>>>(Vtile, Vts);

    // attention (XCD-swizzled flat grid); y overwrites Q columns of qk
    attn<<<dim3(1024), 256, 0, stream>>>(qk, Vt, Vts);

    // gemm2: out = y @ w_proj^T  [4096, 1024] — 128x64 tiles
    gemm_bt64<<<dim3(CC / 64, MT / 128), 256, 0, stream>>>(
        qk, qk, (const bf16*)w_proj, wp_cvt, d_out, flag,
        MT, CC, CC, /*lda*/2048, CC, CC, /*cf32*/1);
}